// Round 3
// baseline (263.401 us; speedup 1.0000x reference)
//
#include <hip/hip_runtime.h>
#include <hip/hip_bf16.h>

#define L_SEQ 2048
#define NH 8
#define DIM 64
#define SS 40
#define UU 40

// ---------------- Kernel 1: M[b,h,l] = max_s(QK_s) - sum_s(QK_s)/L ----------------
// one wave per (b,h,l); lane = g*8+c: group g handles samples {g, g+8, ...},
// lane-in-group c handles d in [c*8, c*8+8)
__global__ __launch_bounds__(256) void m_kernel(const float* __restrict__ Qg,
                                                const float* __restrict__ Kg,
                                                const int* __restrict__ idx,
                                                float* __restrict__ M) {
    int wid = blockIdx.x * 4 + (threadIdx.x >> 6);
    int lane = threadIdx.x & 63;
    int l = wid & (L_SEQ - 1);
    int bh = wid >> 11;
    int b = bh >> 3, h = bh & 7;
    int g = lane >> 3, c = lane & 7;

    const float* Qp = Qg + ((size_t)(b * L_SEQ + l) * NH + h) * DIM + c * 8;
    float4 q0 = *(const float4*)Qp;
    float4 q1 = *(const float4*)(Qp + 4);

    const float* Kbase = Kg + (size_t)b * L_SEQ * NH * DIM + (size_t)h * DIM;

    float mx = -INFINITY, sm = 0.f;
    #pragma unroll
    for (int p = 0; p < 5; ++p) {
        int s = g + p * 8;
        int ki = idx[l * SS + s];
        const float* Kp = Kbase + (size_t)ki * (NH * DIM) + c * 8;
        float4 k0 = *(const float4*)Kp;
        float4 k1 = *(const float4*)(Kp + 4);
        float dot = q0.x * k0.x;
        dot = fmaf(q0.y, k0.y, dot);
        dot = fmaf(q0.z, k0.z, dot);
        dot = fmaf(q0.w, k0.w, dot);
        dot = fmaf(q1.x, k1.x, dot);
        dot = fmaf(q1.y, k1.y, dot);
        dot = fmaf(q1.z, k1.z, dot);
        dot = fmaf(q1.w, k1.w, dot);
        dot += __shfl_xor(dot, 1);
        dot += __shfl_xor(dot, 2);
        dot += __shfl_xor(dot, 4);
        mx = fmaxf(mx, dot);
        sm += dot;
    }
    #pragma unroll
    for (int off = 8; off < 64; off <<= 1) {
        mx = fmaxf(mx, __shfl_xor(mx, off));
        sm += __shfl_xor(sm, off);
    }
    if (lane == 0) M[(size_t)bh * L_SEQ + l] = mx - sm * (1.0f / (float)L_SEQ);
}

// ---------------- Kernel 2: top-40 indices per (b,h), tie -> lower index ----------------
__global__ __launch_bounds__(256) void topk_kernel(const float* __restrict__ M,
                                                   int* __restrict__ Mtop) {
    __shared__ float vals[L_SEQ];
    __shared__ float rv[256];
    __shared__ int ri[256];
    int bh = blockIdx.x, tid = threadIdx.x;
    const float* Mrow = M + (size_t)bh * L_SEQ;
    for (int i = tid; i < L_SEQ; i += 256) vals[i] = Mrow[i];
    __syncthreads();
    for (int t = 0; t < UU; ++t) {
        float bv = -INFINITY; int bi = -1;
        for (int i = tid; i < L_SEQ; i += 256) {
            float v = vals[i];
            if (v > bv || (v == bv && i < bi)) { bv = v; bi = i; }
        }
        rv[tid] = bv; ri[tid] = bi;
        __syncthreads();
        for (int off = 128; off > 0; off >>= 1) {
            if (tid < off) {
                float v2 = rv[tid + off]; int i2 = ri[tid + off];
                if (v2 > rv[tid] || (v2 == rv[tid] && i2 < ri[tid])) { rv[tid] = v2; ri[tid] = i2; }
            }
            __syncthreads();
        }
        if (tid == 0) {
            int w = ri[0] < 0 ? 0 : ri[0];   // defensive: never emit a faulting index
            Mtop[bh * UU + t] = w;
            vals[w] = -INFINITY;
        }
        __syncthreads();
    }
}

// ---------------- Kernel 3: generalized attention over key-splits ----------------
// grid = 32*nsplit blocks; block (bh, sp) processes chunks [sp*cpb, (sp+1)*cpb) of 64 keys,
// online softmax across its chunks. direct=0: emit partial (pm,pl,pO). direct=1 (requires
// nsplit==1): write normalized fp32 rows straight to out (must run after cumsum writes).
__global__ __launch_bounds__(256) void attn_general(
    const float* __restrict__ Qg, const float* __restrict__ Kg,
    const float* __restrict__ Vg, const int* __restrict__ Mtop,
    float* __restrict__ pm, float* __restrict__ pl, float* __restrict__ pO,
    float* __restrict__ out, int nsplit, int direct) {
    __shared__ float qs[UU * DIM];   // 10240 B
    __shared__ float ks[64 * 68];    // 17408 B; reused for V (fp32, stride 68)
    __shared__ float ps[UU * 68];    // 10880 B
    __shared__ float mm[UU], ll[UU], al[UU];
    int bx = blockIdx.x;
    int bh = bx / nsplit, sp = bx - bh * nsplit;
    int b = bh >> 3, h = bh & 7;
    int tid = threadIdx.x;
    int cpb = 32 / nsplit;
    const int* mt = Mtop + bh * UU;

    // gather Q_reduce rows into LDS
    for (int i = tid; i < UU * DIM / 8; i += 256) {
        int u = i >> 3, dv = (i & 7) * 8;
        int row = mt[u];
        const float* qp = Qg + ((size_t)(b * L_SEQ + row) * NH + h) * DIM + dv;
        *(float4*)&qs[u * DIM + dv]     = *(const float4*)qp;
        *(float4*)&qs[u * DIM + dv + 4] = *(const float4*)(qp + 4);
    }
    if (tid < UU) { mm[tid] = -INFINITY; ll[tid] = 0.f; }

    int d0 = (tid & 31) * 2, ugp = tid >> 5;
    float o0[5], o1[5];
    #pragma unroll
    for (int j = 0; j < 5; ++j) { o0[j] = 0.f; o1[j] = 0.f; }

    for (int c = 0; c < cpb; ++c) {
        int k0 = (sp * cpb + c) * 64;
        if (c) __syncthreads();  // prev PV reads of ks(V) done before overwrite
        for (int i = tid; i < 64 * DIM / 8; i += 256) {
            int r = i >> 3, dv = (i & 7) * 8;
            const float* kp = Kg + ((size_t)(b * L_SEQ + k0 + r) * NH + h) * DIM + dv;
            *(float4*)&ks[r * 68 + dv]     = *(const float4*)kp;
            *(float4*)&ks[r * 68 + dv + 4] = *(const float4*)(kp + 4);
        }
        __syncthreads();

        // scores: thread (k = tid&63, 10 u's)
        {
            int k = tid & 63, ug = tid >> 6;
            float acc[10];
            #pragma unroll
            for (int j = 0; j < 10; ++j) acc[j] = 0.f;
            for (int d = 0; d < DIM; d += 4) {
                float4 kv = *(float4*)&ks[k * 68 + d];
                #pragma unroll
                for (int j = 0; j < 10; ++j) {
                    float4 qv = *(float4*)&qs[(ug * 10 + j) * DIM + d];
                    acc[j] = fmaf(qv.x, kv.x, acc[j]);
                    acc[j] = fmaf(qv.y, kv.y, acc[j]);
                    acc[j] = fmaf(qv.z, kv.z, acc[j]);
                    acc[j] = fmaf(qv.w, kv.w, acc[j]);
                }
            }
            #pragma unroll
            for (int j = 0; j < 10; ++j) ps[(ug * 10 + j) * 68 + k] = acc[j] * 0.125f;
        }
        __syncthreads();

        // V chunk -> ks region (fp32, stride 68), concurrent with softmax (disjoint LDS)
        for (int i = tid; i < 64 * DIM / 8; i += 256) {
            int r = i >> 3, dv = (i & 7) * 8;
            const float* vp = Vg + ((size_t)(b * L_SEQ + k0 + r) * NH + h) * DIM + dv;
            *(float4*)&ks[r * 68 + dv]     = *(const float4*)vp;
            *(float4*)&ks[r * 68 + dv + 4] = *(const float4*)(vp + 4);
        }
        if (tid < UU) {
            float mc = -INFINITY;
            for (int k = 0; k < 64; ++k) mc = fmaxf(mc, ps[tid * 68 + k]);
            float mn = fmaxf(mm[tid], mc);
            float a = __expf(mm[tid] - mn);
            float s = 0.f;
            for (int k = 0; k < 64; ++k) {
                float e = __expf(ps[tid * 68 + k] - mn);
                ps[tid * 68 + k] = e;
                s += e;
            }
            ll[tid] = ll[tid] * a + s;
            mm[tid] = mn;
            al[tid] = a;
        }
        __syncthreads();

        // PV: thread (d0 = (tid&31)*2, 5 u's)
        {
            #pragma unroll
            for (int j = 0; j < 5; ++j) {
                float a = al[ugp * 5 + j];
                o0[j] *= a; o1[j] *= a;
            }
            for (int k = 0; k < 64; k += 4) {
                float vf0[4], vf1[4];
                #pragma unroll
                for (int kk = 0; kk < 4; ++kk) {
                    float2 vv = *(float2*)&ks[(k + kk) * 68 + d0];
                    vf0[kk] = vv.x;
                    vf1[kk] = vv.y;
                }
                #pragma unroll
                for (int j = 0; j < 5; ++j) {
                    float4 pv = *(float4*)&ps[(ugp * 5 + j) * 68 + k];
                    o0[j] = fmaf(pv.x, vf0[0], o0[j]); o1[j] = fmaf(pv.x, vf1[0], o1[j]);
                    o0[j] = fmaf(pv.y, vf0[1], o0[j]); o1[j] = fmaf(pv.y, vf1[1], o1[j]);
                    o0[j] = fmaf(pv.z, vf0[2], o0[j]); o1[j] = fmaf(pv.z, vf1[2], o1[j]);
                    o0[j] = fmaf(pv.w, vf0[3], o0[j]); o1[j] = fmaf(pv.w, vf1[3], o1[j]);
                }
            }
        }
    }

    if (!direct) {
        if (tid < UU) {
            pm[((size_t)bh * nsplit + sp) * UU + tid] = mm[tid];
            pl[((size_t)bh * nsplit + sp) * UU + tid] = ll[tid];
        }
        size_t base = ((size_t)bh * nsplit + sp) * UU * DIM;
        #pragma unroll
        for (int j = 0; j < 5; ++j) {
            *(float2*)&pO[base + (size_t)(ugp * 5 + j) * DIM + d0] = make_float2(o0[j], o1[j]);
        }
    } else {
        #pragma unroll
        for (int j = 0; j < 5; ++j) {
            int u = ugp * 5 + j;
            int row = mt[u];
            float inv = 1.0f / ll[u];
            size_t o = ((size_t)(b * L_SEQ + row) * NH + h) * DIM + d0;
            out[o]     = o0[j] * inv;
            out[o + 1] = o1[j] * inv;
        }
    }
}

// ---------------- Kernel 4: cumsum chunk sums ----------------
__global__ __launch_bounds__(256) void csum_partial_kernel(const float* __restrict__ Vg,
                                                           float* __restrict__ cs) {
    int wid = blockIdx.x * 4 + (threadIdx.x >> 6);
    int lane = threadIdx.x & 63;
    int cc = wid & 31, bh = wid >> 5;
    int b = bh >> 3, h = bh & 7;
    const float* Vp = Vg + ((size_t)(b * L_SEQ + cc * 64) * NH + h) * DIM + lane;
    float s = 0.f;
    for (int l = 0; l < 64; ++l) s += Vp[(size_t)l * NH * DIM];
    cs[((size_t)bh * 32 + cc) * DIM + lane] = s;
}

// ---------------- Kernel 5: cumsum write (fills every output element) ----------------
__global__ __launch_bounds__(256) void csum_write_kernel(const float* __restrict__ Vg,
                                                         const float* __restrict__ cs,
                                                         float* __restrict__ out) {
    int wid = blockIdx.x * 4 + (threadIdx.x >> 6);
    int lane = threadIdx.x & 63;
    int cc = wid & 31, bh = wid >> 5;
    int b = bh >> 3, h = bh & 7;
    float run = 0.f;
    for (int c = 0; c < cc; ++c) run += cs[((size_t)bh * 32 + c) * DIM + lane];
    size_t off = ((size_t)(b * L_SEQ + cc * 64) * NH + h) * DIM + lane;
    const float* Vp = Vg + off;
    float* Op = out + off;
    for (int l = 0; l < 64; ++l) {
        run += Vp[(size_t)l * NH * DIM];
        Op[(size_t)l * NH * DIM] = run;
    }
}

// ---------------- Kernel 5b: fused cumsum (no cs buffer; 32 blocks) ----------------
__global__ __launch_bounds__(256) void csum_fused_kernel(const float* __restrict__ Vg,
                                                         float* __restrict__ out) {
    __shared__ float css[32 * 64];
    int bh = blockIdx.x, tid = threadIdx.x;
    int b = bh >> 3, h = bh & 7;
    int cc = tid >> 3, d8 = (tid & 7) * 8;
    size_t off = ((size_t)(b * L_SEQ + cc * 64) * NH + h) * DIM + d8;
    const float* Vp = Vg + off;
    float s[8];
    #pragma unroll
    for (int j = 0; j < 8; ++j) s[j] = 0.f;
    for (int l = 0; l < 64; ++l) {
        float4 r0 = *(const float4*)(Vp + (size_t)l * NH * DIM);
        float4 r1 = *(const float4*)(Vp + (size_t)l * NH * DIM + 4);
        s[0] += r0.x; s[1] += r0.y; s[2] += r0.z; s[3] += r0.w;
        s[4] += r1.x; s[5] += r1.y; s[6] += r1.z; s[7] += r1.w;
    }
    #pragma unroll
    for (int j = 0; j < 8; ++j) css[cc * 64 + d8 + j] = s[j];
    __syncthreads();
    if (tid < 64) {
        float run = 0.f;
        for (int c = 0; c < 32; ++c) {
            float t = css[c * 64 + tid];
            css[c * 64 + tid] = run;
            run += t;
        }
    }
    __syncthreads();
    float r8[8];
    #pragma unroll
    for (int j = 0; j < 8; ++j) r8[j] = css[cc * 64 + d8 + j];
    float* Op = out + off;
    for (int l = 0; l < 64; ++l) {
        float4 r0 = *(const float4*)(Vp + (size_t)l * NH * DIM);
        float4 r1 = *(const float4*)(Vp + (size_t)l * NH * DIM + 4);
        r8[0] += r0.x; r8[1] += r0.y; r8[2] += r0.z; r8[3] += r0.w;
        r8[4] += r1.x; r8[5] += r1.y; r8[6] += r1.z; r8[7] += r1.w;
        *(float4*)(Op + (size_t)l * NH * DIM)     = make_float4(r8[0], r8[1], r8[2], r8[3]);
        *(float4*)(Op + (size_t)l * NH * DIM + 4) = make_float4(r8[4], r8[5], r8[6], r8[7]);
    }
}

// ---------------- Kernel 6: combine partials + scatter attn rows ----------------
__global__ __launch_bounds__(256) void combine_kernel(
    const float* __restrict__ pm, const float* __restrict__ pl,
    const float* __restrict__ pO, const int* __restrict__ Mtop,
    float* __restrict__ out, int nsplit) {
    int wid = blockIdx.x * 4 + (threadIdx.x >> 6); // bh*40+u
    int lane = threadIdx.x & 63;
    int u = wid % UU;
    int bh = wid / UU;
    int b = bh >> 3, h = bh & 7;
    float mg = -INFINITY;
    for (int c = 0; c < nsplit; ++c) mg = fmaxf(mg, pm[((size_t)bh * nsplit + c) * UU + u]);
    float acc = 0.f, lsum = 0.f;
    for (int c = 0; c < nsplit; ++c) {
        size_t pb = ((size_t)bh * nsplit + c) * UU + u;
        float w = __expf(pm[pb] - mg);
        lsum = fmaf(pl[pb], w, lsum);
        acc = fmaf(w, pO[pb * DIM + lane], acc);
    }
    int row = Mtop[bh * UU + u];
    out[((size_t)(b * L_SEQ + row) * NH + h) * DIM + lane] = acc / lsum;
}

extern "C" void kernel_launch(void* const* d_in, const int* in_sizes, int n_in,
                              void* d_out, int out_size, void* d_ws, size_t ws_size,
                              hipStream_t stream) {
    const float* Q = (const float*)d_in[0];
    const float* K = (const float*)d_in[1];
    const float* V = (const float*)d_in[2];
    const int* idx = (const int*)d_in[3];
    float* out = (float*)d_out;
    float* wsf = (float*)d_ws;

    // ws layout (floats): M[65536] | Mtop[1280 as int] | pm[1280n] | pl[1280n]
    //                     | pO[81920n] | cs[65536]   => (132352 + 84480n)*4 bytes
    int n = 0;
    const int cands[5] = {32, 16, 8, 4, 2};
    for (int i = 0; i < 5; ++i) {
        size_t need = (size_t)(132352 + 84480 * cands[i]) * 4;
        if (ws_size >= need) { n = cands[i]; break; }
    }

    if (n > 0) {
        float* M    = wsf;
        int*   Mtop = (int*)(wsf + 65536);
        float* pm   = wsf + 66816;
        float* pl   = pm + 1280 * (size_t)n;
        float* pO   = pl + 1280 * (size_t)n;
        float* cs   = pO + 81920 * (size_t)n;
        m_kernel<<<16384, 256, 0, stream>>>(Q, K, idx, M);
        topk_kernel<<<32, 256, 0, stream>>>(M, Mtop);
        attn_general<<<32 * n, 256, 0, stream>>>(Q, K, V, Mtop, pm, pl, pO, out, n, 0);
        csum_partial_kernel<<<256, 256, 0, stream>>>(V, cs);
        csum_write_kernel<<<256, 256, 0, stream>>>(V, cs, out);
        combine_kernel<<<320, 256, 0, stream>>>(pm, pl, pO, Mtop, out, n);
    } else if (ws_size >= 529408) {
        // M + Mtop + cs in ws; direct single-split attention after cumsum
        float* M    = wsf;
        int*   Mtop = (int*)(wsf + 65536);
        float* cs   = wsf + 66816;
        m_kernel<<<16384, 256, 0, stream>>>(Q, K, idx, M);
        topk_kernel<<<32, 256, 0, stream>>>(M, Mtop);
        csum_partial_kernel<<<256, 256, 0, stream>>>(V, cs);
        csum_write_kernel<<<256, 256, 0, stream>>>(V, cs, out);
        attn_general<<<32, 256, 0, stream>>>(Q, K, V, Mtop, nullptr, nullptr, nullptr, out, 1, 1);
    } else {
        // ultra-slim: M staged in d_out (overwritten later), Mtop in ws (5120 B)
        float* M    = (float*)d_out;
        int*   Mtop = (int*)d_ws;
        m_kernel<<<16384, 256, 0, stream>>>(Q, K, idx, M);
        topk_kernel<<<32, 256, 0, stream>>>(M, Mtop);
        csum_fused_kernel<<<32, 256, 0, stream>>>(V, out);
        attn_general<<<32, 256, 0, stream>>>(Q, K, V, Mtop, nullptr, nullptr, nullptr, out, 1, 1);
    }
}

// Round 4
// 195.212 us; speedup vs baseline: 1.3493x; 1.3493x over previous
//
#include <hip/hip_runtime.h>
#include <hip/hip_bf16.h>

#define L_SEQ 2048
#define NH 8
#define DIM 64
#define SS 40
#define UU 40

// ---------------- Kernel 1: M[b,h,l] = max_s(QK_s) - sum_s(QK_s)/L ----------------
// one wave per (b,h,l); lane = g*8+c: group g handles samples {g, g+8, ...},
// lane-in-group c handles d in [c*8, c*8+8)
__global__ __launch_bounds__(256) void m_kernel(const float* __restrict__ Qg,
                                                const float* __restrict__ Kg,
                                                const int* __restrict__ idx,
                                                float* __restrict__ M) {
    int wid = blockIdx.x * 4 + (threadIdx.x >> 6);
    int lane = threadIdx.x & 63;
    int l = wid & (L_SEQ - 1);
    int bh = wid >> 11;
    int b = bh >> 3, h = bh & 7;
    int g = lane >> 3, c = lane & 7;

    const float* Qp = Qg + ((size_t)(b * L_SEQ + l) * NH + h) * DIM + c * 8;
    float4 q0 = *(const float4*)Qp;
    float4 q1 = *(const float4*)(Qp + 4);

    const float* Kbase = Kg + (size_t)b * L_SEQ * NH * DIM + (size_t)h * DIM;

    float mx = -INFINITY, sm = 0.f;
    #pragma unroll
    for (int p = 0; p < 5; ++p) {
        int s = g + p * 8;
        int ki = idx[l * SS + s];
        const float* Kp = Kbase + (size_t)ki * (NH * DIM) + c * 8;
        float4 k0 = *(const float4*)Kp;
        float4 k1 = *(const float4*)(Kp + 4);
        float dot = q0.x * k0.x;
        dot = fmaf(q0.y, k0.y, dot);
        dot = fmaf(q0.z, k0.z, dot);
        dot = fmaf(q0.w, k0.w, dot);
        dot = fmaf(q1.x, k1.x, dot);
        dot = fmaf(q1.y, k1.y, dot);
        dot = fmaf(q1.z, k1.z, dot);
        dot = fmaf(q1.w, k1.w, dot);
        dot += __shfl_xor(dot, 1);
        dot += __shfl_xor(dot, 2);
        dot += __shfl_xor(dot, 4);
        mx = fmaxf(mx, dot);
        sm += dot;
    }
    #pragma unroll
    for (int off = 8; off < 64; off <<= 1) {
        mx = fmaxf(mx, __shfl_xor(mx, off));
        sm += __shfl_xor(sm, off);
    }
    if (lane == 0) M[(size_t)bh * L_SEQ + l] = mx - sm * (1.0f / (float)L_SEQ);
}

// ---------------- Kernel 2: top-40 per (b,h) via 4-round radix select ----------------
// Order-preserving key transform; ties at the threshold taken at lowest index
// (matches lax.top_k's selected SET; output order is free since downstream is
// a per-row gather/scatter keyed by the same array).
__global__ __launch_bounds__(256) void topk_radix_kernel(const float* __restrict__ M,
                                                         int* __restrict__ Mtop) {
    __shared__ unsigned hist[256];
    __shared__ unsigned suf[256];
    __shared__ int eq_list[64];
    __shared__ unsigned sh_bin, sh_need, sh_cnt, sh_eqc;
    int bh = blockIdx.x, tid = threadIdx.x;
    const float* Mrow = M + (size_t)bh * L_SEQ;
    int base = tid * 8;

    float4 a0 = *(const float4*)(Mrow + base);
    float4 a1 = *(const float4*)(Mrow + base + 4);
    float fv[8] = {a0.x, a0.y, a0.z, a0.w, a1.x, a1.y, a1.z, a1.w};
    unsigned key[8];
    #pragma unroll
    for (int j = 0; j < 8; ++j) {
        unsigned u = __float_as_uint(fv[j]);
        key[j] = (u & 0x80000000u) ? ~u : (u | 0x80000000u);
    }

    unsigned actmask = 0xffu;
    unsigned thresh = 0;
    int need = UU;

    #pragma unroll
    for (int shift = 24; shift >= 0; shift -= 8) {
        hist[tid] = 0;
        __syncthreads();
        #pragma unroll
        for (int j = 0; j < 8; ++j)
            if ((actmask >> j) & 1u)
                atomicAdd(&hist[(key[j] >> shift) & 0xffu], 1u);
        __syncthreads();
        // suffix sums over 256 bins: wave 0 only, shfl-based (no barrier chain)
        if (tid < 64) {
            int b0 = tid * 4;
            unsigned h0 = hist[b0], h1 = hist[b0 + 1], h2 = hist[b0 + 2], h3 = hist[b0 + 3];
            unsigned loc = h0 + h1 + h2 + h3;
            unsigned s = loc;
            #pragma unroll
            for (int off = 1; off < 64; off <<= 1) {
                unsigned o = __shfl_down(s, off, 64);
                if (tid + off < 64) s += o;
            }
            unsigned tail = s - loc;           // sum over lanes > tid
            suf[b0 + 3] = tail;
            suf[b0 + 2] = tail + h3;
            suf[b0 + 1] = tail + h3 + h2;
            suf[b0 + 0] = tail + h3 + h2 + h1;
        }
        __syncthreads();
        // unique boundary bin: suf[b] < need <= suf[b] + hist[b]
        {
            int sb = (int)suf[tid];
            if (sb < need && sb + (int)hist[tid] >= need) {
                sh_bin = (unsigned)tid;
                sh_need = (unsigned)(need - sb);
            }
        }
        __syncthreads();
        unsigned B = sh_bin;
        need = (int)sh_need;
        thresh = (thresh << 8) | B;
        #pragma unroll
        for (int j = 0; j < 8; ++j)
            if ((actmask >> j) & 1u)
                if (((key[j] >> shift) & 0xffu) != B) actmask &= ~(1u << j);
        __syncthreads();
    }

    // selection pass
    if (tid == 0) { sh_cnt = 0; sh_eqc = 0; }
    __syncthreads();
    int* op = Mtop + bh * UU;
    #pragma unroll
    for (int j = 0; j < 8; ++j) {
        if (key[j] > thresh) {
            unsigned p = atomicAdd(&sh_cnt, 1u);
            op[p] = base + j;
        } else if (key[j] == thresh) {
            unsigned p = atomicAdd(&sh_eqc, 1u);
            if (p < 64) eq_list[p] = base + j;
        }
    }
    __syncthreads();
    unsigned cnt = sh_cnt, eqc = sh_eqc;
    // place `need` tie indices (lowest first) at positions [cnt, 40)
    if ((int)eqc == need) {
        if (tid < (unsigned)need) op[cnt + tid] = eq_list[tid];
    } else if (tid == 0) {
        if (eqc <= 64u) {
            // selection-sort the `need` smallest out of eq_list
            for (int t = 0; t < need; ++t) {
                int mi = t;
                for (int j = t + 1; j < (int)eqc; ++j)
                    if (eq_list[j] < eq_list[mi]) mi = j;
                int tmp = eq_list[t]; eq_list[t] = eq_list[mi]; eq_list[mi] = tmp;
                op[cnt + t] = eq_list[t];
            }
        } else {
            // pathological tie flood: serial rescan in index order
            int taken = 0;
            for (int i = 0; i < L_SEQ && taken < need; ++i) {
                unsigned u = __float_as_uint(Mrow[i]);
                unsigned k = (u & 0x80000000u) ? ~u : (u | 0x80000000u);
                if (k == thresh) op[cnt + taken++] = i;
            }
        }
    }
}

// ---------------- Kernel 3: generalized attention over key-splits ----------------
__global__ __launch_bounds__(256) void attn_general(
    const float* __restrict__ Qg, const float* __restrict__ Kg,
    const float* __restrict__ Vg, const int* __restrict__ Mtop,
    float* __restrict__ pm, float* __restrict__ pl, float* __restrict__ pO,
    float* __restrict__ out, int nsplit, int direct) {
    __shared__ float qs[UU * DIM];   // 10240 B
    __shared__ float ks[64 * 68];    // 17408 B; reused for V (fp32, stride 68)
    __shared__ float ps[UU * 68];    // 10880 B
    __shared__ float mm[UU], ll[UU], al[UU];
    int bx = blockIdx.x;
    int bh = bx / nsplit, sp = bx - bh * nsplit;
    int b = bh >> 3, h = bh & 7;
    int tid = threadIdx.x;
    int cpb = 32 / nsplit;
    const int* mt = Mtop + bh * UU;

    for (int i = tid; i < UU * DIM / 8; i += 256) {
        int u = i >> 3, dv = (i & 7) * 8;
        int row = mt[u];
        const float* qp = Qg + ((size_t)(b * L_SEQ + row) * NH + h) * DIM + dv;
        *(float4*)&qs[u * DIM + dv]     = *(const float4*)qp;
        *(float4*)&qs[u * DIM + dv + 4] = *(const float4*)(qp + 4);
    }
    if (tid < UU) { mm[tid] = -INFINITY; ll[tid] = 0.f; }

    int d0 = (tid & 31) * 2, ugp = tid >> 5;
    float o0[5], o1[5];
    #pragma unroll
    for (int j = 0; j < 5; ++j) { o0[j] = 0.f; o1[j] = 0.f; }

    for (int c = 0; c < cpb; ++c) {
        int k0 = (sp * cpb + c) * 64;
        if (c) __syncthreads();
        for (int i = tid; i < 64 * DIM / 8; i += 256) {
            int r = i >> 3, dv = (i & 7) * 8;
            const float* kp = Kg + ((size_t)(b * L_SEQ + k0 + r) * NH + h) * DIM + dv;
            *(float4*)&ks[r * 68 + dv]     = *(const float4*)kp;
            *(float4*)&ks[r * 68 + dv + 4] = *(const float4*)(kp + 4);
        }
        __syncthreads();

        {
            int k = tid & 63, ug = tid >> 6;
            float acc[10];
            #pragma unroll
            for (int j = 0; j < 10; ++j) acc[j] = 0.f;
            for (int d = 0; d < DIM; d += 4) {
                float4 kv = *(float4*)&ks[k * 68 + d];
                #pragma unroll
                for (int j = 0; j < 10; ++j) {
                    float4 qv = *(float4*)&qs[(ug * 10 + j) * DIM + d];
                    acc[j] = fmaf(qv.x, kv.x, acc[j]);
                    acc[j] = fmaf(qv.y, kv.y, acc[j]);
                    acc[j] = fmaf(qv.z, kv.z, acc[j]);
                    acc[j] = fmaf(qv.w, kv.w, acc[j]);
                }
            }
            #pragma unroll
            for (int j = 0; j < 10; ++j) ps[(ug * 10 + j) * 68 + k] = acc[j] * 0.125f;
        }
        __syncthreads();

        for (int i = tid; i < 64 * DIM / 8; i += 256) {
            int r = i >> 3, dv = (i & 7) * 8;
            const float* vp = Vg + ((size_t)(b * L_SEQ + k0 + r) * NH + h) * DIM + dv;
            *(float4*)&ks[r * 68 + dv]     = *(const float4*)vp;
            *(float4*)&ks[r * 68 + dv + 4] = *(const float4*)(vp + 4);
        }
        if (tid < UU) {
            float mc = -INFINITY;
            for (int k = 0; k < 64; ++k) mc = fmaxf(mc, ps[tid * 68 + k]);
            float mn = fmaxf(mm[tid], mc);
            float a = __expf(mm[tid] - mn);
            float s = 0.f;
            for (int k = 0; k < 64; ++k) {
                float e = __expf(ps[tid * 68 + k] - mn);
                ps[tid * 68 + k] = e;
                s += e;
            }
            ll[tid] = ll[tid] * a + s;
            mm[tid] = mn;
            al[tid] = a;
        }
        __syncthreads();

        {
            #pragma unroll
            for (int j = 0; j < 5; ++j) {
                float a = al[ugp * 5 + j];
                o0[j] *= a; o1[j] *= a;
            }
            for (int k = 0; k < 64; k += 4) {
                float vf0[4], vf1[4];
                #pragma unroll
                for (int kk = 0; kk < 4; ++kk) {
                    float2 vv = *(float2*)&ks[(k + kk) * 68 + d0];
                    vf0[kk] = vv.x;
                    vf1[kk] = vv.y;
                }
                #pragma unroll
                for (int j = 0; j < 5; ++j) {
                    float4 pv = *(float4*)&ps[(ugp * 5 + j) * 68 + k];
                    o0[j] = fmaf(pv.x, vf0[0], o0[j]); o1[j] = fmaf(pv.x, vf1[0], o1[j]);
                    o0[j] = fmaf(pv.y, vf0[1], o0[j]); o1[j] = fmaf(pv.y, vf1[1], o1[j]);
                    o0[j] = fmaf(pv.z, vf0[2], o0[j]); o1[j] = fmaf(pv.z, vf1[2], o1[j]);
                    o0[j] = fmaf(pv.w, vf0[3], o0[j]); o1[j] = fmaf(pv.w, vf1[3], o1[j]);
                }
            }
        }
    }

    if (!direct) {
        if (tid < UU) {
            pm[((size_t)bh * nsplit + sp) * UU + tid] = mm[tid];
            pl[((size_t)bh * nsplit + sp) * UU + tid] = ll[tid];
        }
        size_t basep = ((size_t)bh * nsplit + sp) * UU * DIM;
        #pragma unroll
        for (int j = 0; j < 5; ++j) {
            *(float2*)&pO[basep + (size_t)(ugp * 5 + j) * DIM + d0] = make_float2(o0[j], o1[j]);
        }
    } else {
        #pragma unroll
        for (int j = 0; j < 5; ++j) {
            int u = ugp * 5 + j;
            int row = mt[u];
            float inv = 1.0f / ll[u];
            size_t o = ((size_t)(b * L_SEQ + row) * NH + h) * DIM + d0;
            out[o]     = o0[j] * inv;
            out[o + 1] = o1[j] * inv;
        }
    }
}

// ---------------- Kernel 4: cumsum chunk sums ----------------
__global__ __launch_bounds__(256) void csum_partial_kernel(const float* __restrict__ Vg,
                                                           float* __restrict__ cs) {
    int wid = blockIdx.x * 4 + (threadIdx.x >> 6);
    int lane = threadIdx.x & 63;
    int cc = wid & 31, bh = wid >> 5;
    int b = bh >> 3, h = bh & 7;
    const float* Vp = Vg + ((size_t)(b * L_SEQ + cc * 64) * NH + h) * DIM + lane;
    float s = 0.f;
    for (int l = 0; l < 64; ++l) s += Vp[(size_t)l * NH * DIM];
    cs[((size_t)bh * 32 + cc) * DIM + lane] = s;
}

// ---------------- Kernel 5: cumsum write (fills every output element) ----------------
__global__ __launch_bounds__(256) void csum_write_kernel(const float* __restrict__ Vg,
                                                         const float* __restrict__ cs,
                                                         float* __restrict__ out) {
    int wid = blockIdx.x * 4 + (threadIdx.x >> 6);
    int lane = threadIdx.x & 63;
    int cc = wid & 31, bh = wid >> 5;
    int b = bh >> 3, h = bh & 7;
    float run = 0.f;
    for (int c = 0; c < cc; ++c) run += cs[((size_t)bh * 32 + c) * DIM + lane];
    size_t off = ((size_t)(b * L_SEQ + cc * 64) * NH + h) * DIM + lane;
    const float* Vp = Vg + off;
    float* Op = out + off;
    for (int l = 0; l < 64; ++l) {
        run += Vp[(size_t)l * NH * DIM];
        Op[(size_t)l * NH * DIM] = run;
    }
}

// ---------------- Kernel 5b: fused cumsum (no cs buffer; 32 blocks) ----------------
__global__ __launch_bounds__(256) void csum_fused_kernel(const float* __restrict__ Vg,
                                                         float* __restrict__ out) {
    __shared__ float css[32 * 64];
    int bh = blockIdx.x, tid = threadIdx.x;
    int b = bh >> 3, h = bh & 7;
    int cc = tid >> 3, d8 = (tid & 7) * 8;
    size_t off = ((size_t)(b * L_SEQ + cc * 64) * NH + h) * DIM + d8;
    const float* Vp = Vg + off;
    float s[8];
    #pragma unroll
    for (int j = 0; j < 8; ++j) s[j] = 0.f;
    for (int l = 0; l < 64; ++l) {
        float4 r0 = *(const float4*)(Vp + (size_t)l * NH * DIM);
        float4 r1 = *(const float4*)(Vp + (size_t)l * NH * DIM + 4);
        s[0] += r0.x; s[1] += r0.y; s[2] += r0.z; s[3] += r0.w;
        s[4] += r1.x; s[5] += r1.y; s[6] += r1.z; s[7] += r1.w;
    }
    #pragma unroll
    for (int j = 0; j < 8; ++j) css[cc * 64 + d8 + j] = s[j];
    __syncthreads();
    if (tid < 64) {
        float run = 0.f;
        for (int c = 0; c < 32; ++c) {
            float t = css[c * 64 + tid];
            css[c * 64 + tid] = run;
            run += t;
        }
    }
    __syncthreads();
    float r8[8];
    #pragma unroll
    for (int j = 0; j < 8; ++j) r8[j] = css[cc * 64 + d8 + j];
    float* Op = out + off;
    for (int l = 0; l < 64; ++l) {
        float4 r0 = *(const float4*)(Vp + (size_t)l * NH * DIM);
        float4 r1 = *(const float4*)(Vp + (size_t)l * NH * DIM + 4);
        r8[0] += r0.x; r8[1] += r0.y; r8[2] += r0.z; r8[3] += r0.w;
        r8[4] += r1.x; r8[5] += r1.y; r8[6] += r1.z; r8[7] += r1.w;
        *(float4*)(Op + (size_t)l * NH * DIM)     = make_float4(r8[0], r8[1], r8[2], r8[3]);
        *(float4*)(Op + (size_t)l * NH * DIM + 4) = make_float4(r8[4], r8[5], r8[6], r8[7]);
    }
}

// ---------------- Kernel 6: combine partials + scatter attn rows ----------------
__global__ __launch_bounds__(256) void combine_kernel(
    const float* __restrict__ pm, const float* __restrict__ pl,
    const float* __restrict__ pO, const int* __restrict__ Mtop,
    float* __restrict__ out, int nsplit) {
    int wid = blockIdx.x * 4 + (threadIdx.x >> 6); // bh*40+u
    int lane = threadIdx.x & 63;
    int u = wid % UU;
    int bh = wid / UU;
    int b = bh >> 3, h = bh & 7;
    float mg = -INFINITY;
    for (int c = 0; c < nsplit; ++c) mg = fmaxf(mg, pm[((size_t)bh * nsplit + c) * UU + u]);
    float acc = 0.f, lsum = 0.f;
    for (int c = 0; c < nsplit; ++c) {
        size_t pb = ((size_t)bh * nsplit + c) * UU + u;
        float w = __expf(pm[pb] - mg);
        lsum = fmaf(pl[pb], w, lsum);
        acc = fmaf(w, pO[pb * DIM + lane], acc);
    }
    int row = Mtop[bh * UU + u];
    out[((size_t)(b * L_SEQ + row) * NH + h) * DIM + lane] = acc / lsum;
}

extern "C" void kernel_launch(void* const* d_in, const int* in_sizes, int n_in,
                              void* d_out, int out_size, void* d_ws, size_t ws_size,
                              hipStream_t stream) {
    const float* Q = (const float*)d_in[0];
    const float* K = (const float*)d_in[1];
    const float* V = (const float*)d_in[2];
    const int* idx = (const int*)d_in[3];
    float* out = (float*)d_out;
    float* wsf = (float*)d_ws;

    int n = 0;
    const int cands[5] = {32, 16, 8, 4, 2};
    for (int i = 0; i < 5; ++i) {
        size_t need = (size_t)(132352 + 84480 * cands[i]) * 4;
        if (ws_size >= need) { n = cands[i]; break; }
    }

    if (n > 0) {
        float* M    = wsf;
        int*   Mtop = (int*)(wsf + 65536);
        float* pm   = wsf + 66816;
        float* pl   = pm + 1280 * (size_t)n;
        float* pO   = pl + 1280 * (size_t)n;
        float* cs   = pO + 81920 * (size_t)n;
        m_kernel<<<16384, 256, 0, stream>>>(Q, K, idx, M);
        topk_radix_kernel<<<32, 256, 0, stream>>>(M, Mtop);
        attn_general<<<32 * n, 256, 0, stream>>>(Q, K, V, Mtop, pm, pl, pO, out, n, 0);
        csum_partial_kernel<<<256, 256, 0, stream>>>(V, cs);
        csum_write_kernel<<<256, 256, 0, stream>>>(V, cs, out);
        combine_kernel<<<320, 256, 0, stream>>>(pm, pl, pO, Mtop, out, n);
    } else if (ws_size >= 529408) {
        float* M    = wsf;
        int*   Mtop = (int*)(wsf + 65536);
        float* cs   = wsf + 66816;
        m_kernel<<<16384, 256, 0, stream>>>(Q, K, idx, M);
        topk_radix_kernel<<<32, 256, 0, stream>>>(M, Mtop);
        csum_partial_kernel<<<256, 256, 0, stream>>>(V, cs);
        csum_write_kernel<<<256, 256, 0, stream>>>(V, cs, out);
        attn_general<<<32, 256, 0, stream>>>(Q, K, V, Mtop, nullptr, nullptr, nullptr, out, 1, 1);
    } else {
        float* M    = (float*)d_out;
        int*   Mtop = (int*)d_ws;
        m_kernel<<<16384, 256, 0, stream>>>(Q, K, idx, M);
        topk_radix_kernel<<<32, 256, 0, stream>>>(M, Mtop);
        csum_fused_kernel<<<32, 256, 0, stream>>>(V, out);
        attn_general<<<32, 256, 0, stream>>>(Q, K, V, Mtop, nullptr, nullptr, nullptr, out, 1, 1);
    }
}

// Round 5
// 191.385 us; speedup vs baseline: 1.3763x; 1.0200x over previous
//
#include <hip/hip_runtime.h>
#include <hip/hip_bf16.h>

#define L_SEQ 2048
#define NH 8
#define DIM 64
#define SS 40
#define UU 40
#define NHD (NH * DIM)   // 512 floats between consecutive l rows

// ---------------- Kernel 1: M[b,h,l] = max_s(QK_s) - sum_s(QK_s)/L ----------------
// XCD-pinned swizzle: bh = blockIdx&31 -> blockIdx%8 == bh%8, so each (b,h) K-slice
// (512 KB) stays resident in ONE XCD's L2 instead of being fetched by all 8.
// All 5 idx loads then all 10 K float4 loads hoisted -> 10 outstanding loads/wave.
// Lane c reads floats [4c,4c+4) and [32+4c,32+4c+4): each dwordx4 instr covers a
// whole 128B line across the 8 lanes of a sample group.
__global__ __launch_bounds__(256) void m_kernel(const float* __restrict__ Qg,
                                                const float* __restrict__ Kg,
                                                const int* __restrict__ idx,
                                                float* __restrict__ M) {
    int B = blockIdx.x;
    int bh = B & 31;                       // pinned: bh%8 == B%8 (XCD round-robin)
    int l  = (B >> 5) * 4 + (threadIdx.x >> 6);
    int lane = threadIdx.x & 63;
    int b = bh >> 3, h = bh & 7;
    int g = lane >> 3, c = lane & 7;

    const float* Qp = Qg + ((size_t)(b * L_SEQ + l) * NH + h) * DIM;
    const int* ip = idx + l * SS + g;
    int ki0 = ip[0], ki1 = ip[8], ki2 = ip[16], ki3 = ip[24], ki4 = ip[32];

    float4 q0 = *(const float4*)(Qp + 4 * c);
    float4 q1 = *(const float4*)(Qp + 32 + 4 * c);

    const float* Kbase = Kg + (size_t)b * L_SEQ * NHD + (size_t)h * DIM;
    const float* r0 = Kbase + (size_t)ki0 * NHD;
    const float* r1 = Kbase + (size_t)ki1 * NHD;
    const float* r2 = Kbase + (size_t)ki2 * NHD;
    const float* r3 = Kbase + (size_t)ki3 * NHD;
    const float* r4 = Kbase + (size_t)ki4 * NHD;

    // all 10 loads issued before any dependent compute
    float4 a0 = *(const float4*)(r0 + 4 * c), b0 = *(const float4*)(r0 + 32 + 4 * c);
    float4 a1 = *(const float4*)(r1 + 4 * c), b1 = *(const float4*)(r1 + 32 + 4 * c);
    float4 a2 = *(const float4*)(r2 + 4 * c), b2 = *(const float4*)(r2 + 32 + 4 * c);
    float4 a3 = *(const float4*)(r3 + 4 * c), b3 = *(const float4*)(r3 + 32 + 4 * c);
    float4 a4 = *(const float4*)(r4 + 4 * c), b4 = *(const float4*)(r4 + 32 + 4 * c);

#define DOT8(ka, kb, out) { \
    float d_ = ka.x * q0.x; \
    d_ = fmaf(ka.y, q0.y, d_); d_ = fmaf(ka.z, q0.z, d_); d_ = fmaf(ka.w, q0.w, d_); \
    d_ = fmaf(kb.x, q1.x, d_); d_ = fmaf(kb.y, q1.y, d_); \
    d_ = fmaf(kb.z, q1.z, d_); d_ = fmaf(kb.w, q1.w, d_); \
    d_ += __shfl_xor(d_, 1); d_ += __shfl_xor(d_, 2); d_ += __shfl_xor(d_, 4); \
    out = d_; }

    float d0, d1, d2, d3, d4;   // 5 independent shfl chains
    DOT8(a0, b0, d0); DOT8(a1, b1, d1); DOT8(a2, b2, d2);
    DOT8(a3, b3, d3); DOT8(a4, b4, d4);
#undef DOT8

    float mx = fmaxf(fmaxf(fmaxf(d0, d1), fmaxf(d2, d3)), d4);
    float sm = d0 + d1 + d2 + d3 + d4;
    #pragma unroll
    for (int off = 8; off < 64; off <<= 1) {
        mx = fmaxf(mx, __shfl_xor(mx, off));
        sm += __shfl_xor(sm, off);
    }
    if (lane == 0) M[(size_t)bh * L_SEQ + l] = mx - sm * (1.0f / (float)L_SEQ);
}

// ---------------- Kernel 2: top-40 per (b,h) via 4-round radix select ----------------
__global__ __launch_bounds__(256) void topk_radix_kernel(const float* __restrict__ M,
                                                         int* __restrict__ Mtop) {
    __shared__ unsigned hist[256];
    __shared__ unsigned suf[256];
    __shared__ int eq_list[64];
    __shared__ unsigned sh_bin, sh_need, sh_cnt, sh_eqc;
    int bh = blockIdx.x, tid = threadIdx.x;
    const float* Mrow = M + (size_t)bh * L_SEQ;
    int base = tid * 8;

    float4 a0 = *(const float4*)(Mrow + base);
    float4 a1 = *(const float4*)(Mrow + base + 4);
    float fv[8] = {a0.x, a0.y, a0.z, a0.w, a1.x, a1.y, a1.z, a1.w};
    unsigned key[8];
    #pragma unroll
    for (int j = 0; j < 8; ++j) {
        unsigned u = __float_as_uint(fv[j]);
        key[j] = (u & 0x80000000u) ? ~u : (u | 0x80000000u);
    }

    unsigned actmask = 0xffu;
    unsigned thresh = 0;
    int need = UU;

    #pragma unroll
    for (int shift = 24; shift >= 0; shift -= 8) {
        hist[tid] = 0;
        __syncthreads();
        #pragma unroll
        for (int j = 0; j < 8; ++j)
            if ((actmask >> j) & 1u)
                atomicAdd(&hist[(key[j] >> shift) & 0xffu], 1u);
        __syncthreads();
        if (tid < 64) {
            int b0 = tid * 4;
            unsigned h0 = hist[b0], h1 = hist[b0 + 1], h2 = hist[b0 + 2], h3 = hist[b0 + 3];
            unsigned loc = h0 + h1 + h2 + h3;
            unsigned s = loc;
            #pragma unroll
            for (int off = 1; off < 64; off <<= 1) {
                unsigned o = __shfl_down(s, off, 64);
                if (tid + off < 64) s += o;
            }
            unsigned tail = s - loc;
            suf[b0 + 3] = tail;
            suf[b0 + 2] = tail + h3;
            suf[b0 + 1] = tail + h3 + h2;
            suf[b0 + 0] = tail + h3 + h2 + h1;
        }
        __syncthreads();
        {
            int sb = (int)suf[tid];
            if (sb < need && sb + (int)hist[tid] >= need) {
                sh_bin = (unsigned)tid;
                sh_need = (unsigned)(need - sb);
            }
        }
        __syncthreads();
        unsigned Bb = sh_bin;
        need = (int)sh_need;
        thresh = (thresh << 8) | Bb;
        #pragma unroll
        for (int j = 0; j < 8; ++j)
            if ((actmask >> j) & 1u)
                if (((key[j] >> shift) & 0xffu) != Bb) actmask &= ~(1u << j);
        __syncthreads();
    }

    if (tid == 0) { sh_cnt = 0; sh_eqc = 0; }
    __syncthreads();
    int* op = Mtop + bh * UU;
    #pragma unroll
    for (int j = 0; j < 8; ++j) {
        if (key[j] > thresh) {
            unsigned p = atomicAdd(&sh_cnt, 1u);
            op[p] = base + j;
        } else if (key[j] == thresh) {
            unsigned p = atomicAdd(&sh_eqc, 1u);
            if (p < 64) eq_list[p] = base + j;
        }
    }
    __syncthreads();
    unsigned cnt = sh_cnt, eqc = sh_eqc;
    if ((int)eqc == need) {
        if (tid < (unsigned)need) op[cnt + tid] = eq_list[tid];
    } else if (tid == 0) {
        if (eqc <= 64u) {
            for (int t = 0; t < need; ++t) {
                int mi = t;
                for (int j = t + 1; j < (int)eqc; ++j)
                    if (eq_list[j] < eq_list[mi]) mi = j;
                int tmp = eq_list[t]; eq_list[t] = eq_list[mi]; eq_list[mi] = tmp;
                op[cnt + t] = eq_list[t];
            }
        } else {
            int taken = 0;
            for (int i = 0; i < L_SEQ && taken < need; ++i) {
                unsigned u = __float_as_uint(Mrow[i]);
                unsigned k = (u & 0x80000000u) ? ~u : (u | 0x80000000u);
                if (k == thresh) op[cnt + taken++] = i;
            }
        }
    }
}

// ---------------- Kernel 3: generalized attention over key-splits ----------------
__global__ __launch_bounds__(256) void attn_general(
    const float* __restrict__ Qg, const float* __restrict__ Kg,
    const float* __restrict__ Vg, const int* __restrict__ Mtop,
    float* __restrict__ pm, float* __restrict__ pl, float* __restrict__ pO,
    float* __restrict__ out, int nsplit, int direct) {
    __shared__ float qs[UU * DIM];
    __shared__ float ks[64 * 68];
    __shared__ float ps[UU * 68];
    __shared__ float mm[UU], ll[UU], al[UU];
    int bx = blockIdx.x;
    int bh = bx / nsplit, sp = bx - bh * nsplit;
    int b = bh >> 3, h = bh & 7;
    int tid = threadIdx.x;
    int cpb = 32 / nsplit;
    const int* mt = Mtop + bh * UU;

    for (int i = tid; i < UU * DIM / 8; i += 256) {
        int u = i >> 3, dv = (i & 7) * 8;
        int row = mt[u];
        const float* qp = Qg + ((size_t)(b * L_SEQ + row) * NH + h) * DIM + dv;
        *(float4*)&qs[u * DIM + dv]     = *(const float4*)qp;
        *(float4*)&qs[u * DIM + dv + 4] = *(const float4*)(qp + 4);
    }
    if (tid < UU) { mm[tid] = -INFINITY; ll[tid] = 0.f; }

    int d0 = (tid & 31) * 2, ugp = tid >> 5;
    float o0[5], o1[5];
    #pragma unroll
    for (int j = 0; j < 5; ++j) { o0[j] = 0.f; o1[j] = 0.f; }

    for (int c = 0; c < cpb; ++c) {
        int k0 = (sp * cpb + c) * 64;
        if (c) __syncthreads();
        for (int i = tid; i < 64 * DIM / 8; i += 256) {
            int r = i >> 3, dv = (i & 7) * 8;
            const float* kp = Kg + ((size_t)(b * L_SEQ + k0 + r) * NH + h) * DIM + dv;
            *(float4*)&ks[r * 68 + dv]     = *(const float4*)kp;
            *(float4*)&ks[r * 68 + dv + 4] = *(const float4*)(kp + 4);
        }
        __syncthreads();

        {
            int k = tid & 63, ug = tid >> 6;
            float acc[10];
            #pragma unroll
            for (int j = 0; j < 10; ++j) acc[j] = 0.f;
            for (int d = 0; d < DIM; d += 4) {
                float4 kv = *(float4*)&ks[k * 68 + d];
                #pragma unroll
                for (int j = 0; j < 10; ++j) {
                    float4 qv = *(float4*)&qs[(ug * 10 + j) * DIM + d];
                    acc[j] = fmaf(qv.x, kv.x, acc[j]);
                    acc[j] = fmaf(qv.y, kv.y, acc[j]);
                    acc[j] = fmaf(qv.z, kv.z, acc[j]);
                    acc[j] = fmaf(qv.w, kv.w, acc[j]);
                }
            }
            #pragma unroll
            for (int j = 0; j < 10; ++j) ps[(ug * 10 + j) * 68 + k] = acc[j] * 0.125f;
        }
        __syncthreads();

        for (int i = tid; i < 64 * DIM / 8; i += 256) {
            int r = i >> 3, dv = (i & 7) * 8;
            const float* vp = Vg + ((size_t)(b * L_SEQ + k0 + r) * NH + h) * DIM + dv;
            *(float4*)&ks[r * 68 + dv]     = *(const float4*)vp;
            *(float4*)&ks[r * 68 + dv + 4] = *(const float4*)(vp + 4);
        }
        if (tid < UU) {
            float mc = -INFINITY;
            for (int k = 0; k < 64; ++k) mc = fmaxf(mc, ps[tid * 68 + k]);
            float mn = fmaxf(mm[tid], mc);
            float a = __expf(mm[tid] - mn);
            float s = 0.f;
            for (int k = 0; k < 64; ++k) {
                float e = __expf(ps[tid * 68 + k] - mn);
                ps[tid * 68 + k] = e;
                s += e;
            }
            ll[tid] = ll[tid] * a + s;
            mm[tid] = mn;
            al[tid] = a;
        }
        __syncthreads();

        {
            #pragma unroll
            for (int j = 0; j < 5; ++j) {
                float a = al[ugp * 5 + j];
                o0[j] *= a; o1[j] *= a;
            }
            for (int k = 0; k < 64; k += 4) {
                float vf0[4], vf1[4];
                #pragma unroll
                for (int kk = 0; kk < 4; ++kk) {
                    float2 vv = *(float2*)&ks[(k + kk) * 68 + d0];
                    vf0[kk] = vv.x;
                    vf1[kk] = vv.y;
                }
                #pragma unroll
                for (int j = 0; j < 5; ++j) {
                    float4 pv = *(float4*)&ps[(ugp * 5 + j) * 68 + k];
                    o0[j] = fmaf(pv.x, vf0[0], o0[j]); o1[j] = fmaf(pv.x, vf1[0], o1[j]);
                    o0[j] = fmaf(pv.y, vf0[1], o0[j]); o1[j] = fmaf(pv.y, vf1[1], o1[j]);
                    o0[j] = fmaf(pv.z, vf0[2], o0[j]); o1[j] = fmaf(pv.z, vf1[2], o1[j]);
                    o0[j] = fmaf(pv.w, vf0[3], o0[j]); o1[j] = fmaf(pv.w, vf1[3], o1[j]);
                }
            }
        }
    }

    if (!direct) {
        if (tid < UU) {
            pm[((size_t)bh * nsplit + sp) * UU + tid] = mm[tid];
            pl[((size_t)bh * nsplit + sp) * UU + tid] = ll[tid];
        }
        size_t basep = ((size_t)bh * nsplit + sp) * UU * DIM;
        #pragma unroll
        for (int j = 0; j < 5; ++j) {
            *(float2*)&pO[basep + (size_t)(ugp * 5 + j) * DIM + d0] = make_float2(o0[j], o1[j]);
        }
    } else {
        #pragma unroll
        for (int j = 0; j < 5; ++j) {
            int u = ugp * 5 + j;
            int row = mt[u];
            float inv = 1.0f / ll[u];
            size_t o = ((size_t)(b * L_SEQ + row) * NH + h) * DIM + d0;
            out[o]     = o0[j] * inv;
            out[o + 1] = o1[j] * inv;
        }
    }
}

// ---------------- cumsum v2: 8-row granularity, 8192 waves per phase ----------------
// Phase A: cs8[bh][c8][d] = sum of 8 V rows   (wid = bh*256 + c8)
__global__ __launch_bounds__(256) void csum8_kernel(const float* __restrict__ Vg,
                                                    float* __restrict__ cs8) {
    int wid = blockIdx.x * 4 + (threadIdx.x >> 6);   // 0..8191
    int lane = threadIdx.x & 63;
    int c8 = wid & 255, bh = wid >> 8;
    int b = bh >> 3, h = bh & 7;
    const float* Vp = Vg + ((size_t)(b * L_SEQ + c8 * 8) * NH + h) * DIM + lane;
    float s = 0.f;
    #pragma unroll
    for (int j = 0; j < 8; ++j) s += Vp[(size_t)j * NHD];
    cs8[((size_t)bh * 256 + c8) * 64 + lane] = s;
}

// Phase B: in-place exclusive prefix over the 256 chunk-sums per (bh, d).
// One block per bh; 64 KB LDS stage; scan threads d=0..63 hit banks 2-way (free).
__global__ __launch_bounds__(256) void prefix8_kernel(float* __restrict__ cs8) {
    __shared__ float buf[256 * 64];
    int bh = blockIdx.x, tid = threadIdx.x;
    float* g = cs8 + (size_t)bh * 16384;
    for (int it = 0; it < 16; ++it) {
        int i = it * 1024 + tid * 4;
        *(float4*)&buf[i] = *(const float4*)&g[i];
    }
    __syncthreads();
    if (tid < 64) {
        float run = 0.f;
        for (int c = 0; c < 256; ++c) {
            float t = buf[c * 64 + tid];
            buf[c * 64 + tid] = run;
            run += t;
        }
    }
    __syncthreads();
    for (int it = 0; it < 16; ++it) {
        int i = it * 1024 + tid * 4;
        *(float4*)&g[i] = *(const float4*)&buf[i];
    }
}

// Phase C: out rows = exclusive prefix + running sum of 8 V rows
__global__ __launch_bounds__(256) void csum_write8_kernel(const float* __restrict__ Vg,
                                                          const float* __restrict__ cs8,
                                                          float* __restrict__ out) {
    int wid = blockIdx.x * 4 + (threadIdx.x >> 6);   // 0..8191
    int lane = threadIdx.x & 63;
    int c8 = wid & 255, bh = wid >> 8;
    int b = bh >> 3, h = bh & 7;
    float run = cs8[((size_t)bh * 256 + c8) * 64 + lane];
    size_t off = ((size_t)(b * L_SEQ + c8 * 8) * NH + h) * DIM + lane;
    const float* Vp = Vg + off;
    float* Op = out + off;
    #pragma unroll
    for (int j = 0; j < 8; ++j) {
        run += Vp[(size_t)j * NHD];
        Op[(size_t)j * NHD] = run;
    }
}

// ---------------- fused cumsum fallback (ultra-slim ws) ----------------
__global__ __launch_bounds__(256) void csum_fused_kernel(const float* __restrict__ Vg,
                                                         float* __restrict__ out) {
    __shared__ float css[32 * 64];
    int bh = blockIdx.x, tid = threadIdx.x;
    int b = bh >> 3, h = bh & 7;
    int cc = tid >> 3, d8 = (tid & 7) * 8;
    size_t off = ((size_t)(b * L_SEQ + cc * 64) * NH + h) * DIM + d8;
    const float* Vp = Vg + off;
    float s[8];
    #pragma unroll
    for (int j = 0; j < 8; ++j) s[j] = 0.f;
    for (int l = 0; l < 64; ++l) {
        float4 r0 = *(const float4*)(Vp + (size_t)l * NHD);
        float4 r1 = *(const float4*)(Vp + (size_t)l * NHD + 4);
        s[0] += r0.x; s[1] += r0.y; s[2] += r0.z; s[3] += r0.w;
        s[4] += r1.x; s[5] += r1.y; s[6] += r1.z; s[7] += r1.w;
    }
    #pragma unroll
    for (int j = 0; j < 8; ++j) css[cc * 64 + d8 + j] = s[j];
    __syncthreads();
    if (tid < 64) {
        float run = 0.f;
        for (int c = 0; c < 32; ++c) {
            float t = css[c * 64 + tid];
            css[c * 64 + tid] = run;
            run += t;
        }
    }
    __syncthreads();
    float r8[8];
    #pragma unroll
    for (int j = 0; j < 8; ++j) r8[j] = css[cc * 64 + d8 + j];
    float* Op = out + off;
    for (int l = 0; l < 64; ++l) {
        float4 r0 = *(const float4*)(Vp + (size_t)l * NHD);
        float4 r1 = *(const float4*)(Vp + (size_t)l * NHD + 4);
        r8[0] += r0.x; r8[1] += r0.y; r8[2] += r0.z; r8[3] += r0.w;
        r8[4] += r1.x; r8[5] += r1.y; r8[6] += r1.z; r8[7] += r1.w;
        *(float4*)(Op + (size_t)l * NHD)     = make_float4(r8[0], r8[1], r8[2], r8[3]);
        *(float4*)(Op + (size_t)l * NHD + 4) = make_float4(r8[4], r8[5], r8[6], r8[7]);
    }
}

// ---------------- combine partials + scatter attn rows ----------------
__global__ __launch_bounds__(256) void combine_kernel(
    const float* __restrict__ pm, const float* __restrict__ pl,
    const float* __restrict__ pO, const int* __restrict__ Mtop,
    float* __restrict__ out, int nsplit) {
    int wid = blockIdx.x * 4 + (threadIdx.x >> 6);
    int lane = threadIdx.x & 63;
    int u = wid % UU;
    int bh = wid / UU;
    int b = bh >> 3, h = bh & 7;
    float mg = -INFINITY;
    for (int c = 0; c < nsplit; ++c) mg = fmaxf(mg, pm[((size_t)bh * nsplit + c) * UU + u]);
    float acc = 0.f, lsum = 0.f;
    for (int c = 0; c < nsplit; ++c) {
        size_t pb = ((size_t)bh * nsplit + c) * UU + u;
        float w = __expf(pm[pb] - mg);
        lsum = fmaf(pl[pb], w, lsum);
        acc = fmaf(w, pO[pb * DIM + lane], acc);
    }
    int row = Mtop[bh * UU + u];
    out[((size_t)(b * L_SEQ + row) * NH + h) * DIM + lane] = acc / lsum;
}

extern "C" void kernel_launch(void* const* d_in, const int* in_sizes, int n_in,
                              void* d_out, int out_size, void* d_ws, size_t ws_size,
                              hipStream_t stream) {
    const float* Q = (const float*)d_in[0];
    const float* K = (const float*)d_in[1];
    const float* V = (const float*)d_in[2];
    const int* idx = (const int*)d_in[3];
    float* out = (float*)d_out;
    float* wsf = (float*)d_ws;

    // ws layout (floats): M[65536] | Mtop[1280 int] | pm[1280n] | pl[1280n]
    //                     | pO[81920n] | cs8[524288]  => (591104 + 84480n)*4 bytes
    int n = 0;
    const int cands[5] = {32, 16, 8, 4, 2};
    for (int i = 0; i < 5; ++i) {
        size_t need = (size_t)(591104 + 84480 * cands[i]) * 4;
        if (ws_size >= need) { n = cands[i]; break; }
    }

    if (n > 0) {
        float* M    = wsf;
        int*   Mtop = (int*)(wsf + 65536);
        float* pm   = wsf + 66816;
        float* pl   = pm + 1280 * (size_t)n;
        float* pO   = pl + 1280 * (size_t)n;
        float* cs8  = pO + 81920 * (size_t)n;
        m_kernel<<<16384, 256, 0, stream>>>(Q, K, idx, M);
        topk_radix_kernel<<<32, 256, 0, stream>>>(M, Mtop);
        attn_general<<<32 * n, 256, 0, stream>>>(Q, K, V, Mtop, pm, pl, pO, out, n, 0);
        csum8_kernel<<<2048, 256, 0, stream>>>(V, cs8);
        prefix8_kernel<<<32, 256, 0, stream>>>(cs8);
        csum_write8_kernel<<<2048, 256, 0, stream>>>(V, cs8, out);
        combine_kernel<<<320, 256, 0, stream>>>(pm, pl, pO, Mtop, out, n);
    } else if (ws_size >= (size_t)(66816 + 524288) * 4) {
        float* M    = wsf;
        int*   Mtop = (int*)(wsf + 65536);
        float* cs8  = wsf + 66816;
        m_kernel<<<16384, 256, 0, stream>>>(Q, K, idx, M);
        topk_radix_kernel<<<32, 256, 0, stream>>>(M, Mtop);
        csum8_kernel<<<2048, 256, 0, stream>>>(V, cs8);
        prefix8_kernel<<<32, 256, 0, stream>>>(cs8);
        csum_write8_kernel<<<2048, 256, 0, stream>>>(V, cs8, out);
        attn_general<<<32, 256, 0, stream>>>(Q, K, V, Mtop, nullptr, nullptr, nullptr, out, 1, 1);
    } else {
        float* M    = (float*)d_out;
        int*   Mtop = (int*)d_ws;
        m_kernel<<<16384, 256, 0, stream>>>(Q, K, idx, M);
        topk_radix_kernel<<<32, 256, 0, stream>>>(M, Mtop);
        csum_fused_kernel<<<32, 256, 0, stream>>>(V, out);
        attn_general<<<32, 256, 0, stream>>>(Q, K, V, Mtop, nullptr, nullptr, nullptr, out, 1, 1);
    }
}

// Round 6
// 177.673 us; speedup vs baseline: 1.4825x; 1.0772x over previous
//
#include <hip/hip_runtime.h>

#define L_SEQ 2048
#define NH 8
#define DIM 64
#define SS 40
#define UU 40
#define NHD 512   // NH*DIM floats between consecutive l rows

// ======================= device bodies =======================

// m-score: wave handles one (b,l), all 8 heads. lane = h*8+c; per sample the
// wave reads K[b,ki,:,:] as one contiguous 2KB block (perfectly coalesced).
__device__ __forceinline__ void m_body(const float* __restrict__ Qg,
                                       const float* __restrict__ Kg,
                                       const int* __restrict__ idx,
                                       float* __restrict__ M,
                                       int bx, int tid) {
    int lane = tid & 63;
    int b = bx & 3;                       // XCD-pinned: bx%8 fixes b -> K-slice per-L2
    int l = (bx >> 2) * 4 + (tid >> 6);
    int h = lane >> 3, c = lane & 7;

    const float* Qp = Qg + ((size_t)(b * L_SEQ + l) * NH + h) * DIM + c * 8;
    float4 q0 = *(const float4*)Qp;
    float4 q1 = *(const float4*)(Qp + 4);
    const float* Kbase = Kg + (size_t)b * L_SEQ * NHD + h * DIM + c * 8;
    const int* ip = idx + l * SS;         // wave-uniform -> scalar loads

    float mx = -INFINITY, sm = 0.f;
#define DOT8(ka, kb, out) { \
    float d_ = ka.x * q0.x; \
    d_ = fmaf(ka.y, q0.y, d_); d_ = fmaf(ka.z, q0.z, d_); d_ = fmaf(ka.w, q0.w, d_); \
    d_ = fmaf(kb.x, q1.x, d_); d_ = fmaf(kb.y, q1.y, d_); \
    d_ = fmaf(kb.z, q1.z, d_); d_ = fmaf(kb.w, q1.w, d_); \
    d_ += __shfl_xor(d_, 1); d_ += __shfl_xor(d_, 2); d_ += __shfl_xor(d_, 4); \
    out = d_; }
    #pragma unroll
    for (int s = 0; s < SS; s += 5) {
        int k0 = ip[s], k1 = ip[s+1], k2 = ip[s+2], k3 = ip[s+3], k4 = ip[s+4];
        const float* r0 = Kbase + (size_t)k0 * NHD;
        const float* r1 = Kbase + (size_t)k1 * NHD;
        const float* r2 = Kbase + (size_t)k2 * NHD;
        const float* r3 = Kbase + (size_t)k3 * NHD;
        const float* r4 = Kbase + (size_t)k4 * NHD;
        float4 a0 = *(const float4*)r0, b0 = *(const float4*)(r0 + 4);
        float4 a1 = *(const float4*)r1, b1 = *(const float4*)(r1 + 4);
        float4 a2 = *(const float4*)r2, b2 = *(const float4*)(r2 + 4);
        float4 a3 = *(const float4*)r3, b3 = *(const float4*)(r3 + 4);
        float4 a4 = *(const float4*)r4, b4 = *(const float4*)(r4 + 4);
        float d0, d1, d2, d3, d4;
        DOT8(a0, b0, d0); DOT8(a1, b1, d1); DOT8(a2, b2, d2);
        DOT8(a3, b3, d3); DOT8(a4, b4, d4);
        mx = fmaxf(mx, fmaxf(fmaxf(d0, d1), fmaxf(fmaxf(d2, d3), d4)));
        sm += d0 + d1 + d2 + d3 + d4;
    }
#undef DOT8
    if (c == 0) M[((size_t)(b * NH + h)) * L_SEQ + l] = mx - sm * (1.0f / (float)L_SEQ);
}

// csum8 phase A: cs8[bh][c8][d] = sum of 8 V rows
__device__ __forceinline__ void csum8_body(const float* __restrict__ Vg,
                                           float* __restrict__ cs8,
                                           int wid, int lane) {
    int c8 = wid & 255, bh = wid >> 8;
    int b = bh >> 3, h = bh & 7;
    const float* Vp = Vg + ((size_t)(b * L_SEQ + c8 * 8) * NH + h) * DIM + lane;
    float s = 0.f;
    #pragma unroll
    for (int j = 0; j < 8; ++j) s += Vp[(size_t)j * NHD];
    cs8[((size_t)bh * 256 + c8) * 64 + lane] = s;
}

// csum8 phase C: out rows = exclusive prefix + running sum of 8 V rows
__device__ __forceinline__ void write8_body(const float* __restrict__ Vg,
                                            const float* __restrict__ cs8,
                                            float* __restrict__ out,
                                            int wid, int lane) {
    int c8 = wid & 255, bh = wid >> 8;
    int b = bh >> 3, h = bh & 7;
    float run = cs8[((size_t)bh * 256 + c8) * 64 + lane];
    size_t off = ((size_t)(b * L_SEQ + c8 * 8) * NH + h) * DIM + lane;
    const float* Vp = Vg + off;
    float* Op = out + off;
    #pragma unroll
    for (int j = 0; j < 8; ++j) {
        run += Vp[(size_t)j * NHD];
        Op[(size_t)j * NHD] = run;
    }
}

// attention over key-splits (online softmax within block)
__device__ void attn_body(const float* __restrict__ Qg, const float* __restrict__ Kg,
                          const float* __restrict__ Vg, const int* __restrict__ Mtop,
                          float* __restrict__ pm, float* __restrict__ pl,
                          float* __restrict__ pO, float* __restrict__ out,
                          int nsplit, int direct, int bx, int tid,
                          float* qs, float* ks, float* ps,
                          float* mm, float* ll, float* al) {
    int bh = bx / nsplit, sp = bx - bh * nsplit;
    int b = bh >> 3, h = bh & 7;
    int cpb = 32 / nsplit;
    const int* mt = Mtop + bh * UU;

    for (int i = tid; i < UU * DIM / 8; i += 256) {
        int u = i >> 3, dv = (i & 7) * 8;
        int row = mt[u];
        const float* qp = Qg + ((size_t)(b * L_SEQ + row) * NH + h) * DIM + dv;
        *(float4*)&qs[u * DIM + dv]     = *(const float4*)qp;
        *(float4*)&qs[u * DIM + dv + 4] = *(const float4*)(qp + 4);
    }
    if (tid < UU) { mm[tid] = -INFINITY; ll[tid] = 0.f; }

    int d0 = (tid & 31) * 2, ugp = tid >> 5;
    float o0[5], o1[5];
    #pragma unroll
    for (int j = 0; j < 5; ++j) { o0[j] = 0.f; o1[j] = 0.f; }

    for (int c = 0; c < cpb; ++c) {
        int k0 = (sp * cpb + c) * 64;
        if (c) __syncthreads();
        for (int i = tid; i < 64 * DIM / 8; i += 256) {
            int r = i >> 3, dv = (i & 7) * 8;
            const float* kp = Kg + ((size_t)(b * L_SEQ + k0 + r) * NH + h) * DIM + dv;
            *(float4*)&ks[r * 68 + dv]     = *(const float4*)kp;
            *(float4*)&ks[r * 68 + dv + 4] = *(const float4*)(kp + 4);
        }
        __syncthreads();

        {
            int k = tid & 63, ug = tid >> 6;
            float acc[10];
            #pragma unroll
            for (int j = 0; j < 10; ++j) acc[j] = 0.f;
            for (int d = 0; d < DIM; d += 4) {
                float4 kv = *(float4*)&ks[k * 68 + d];
                #pragma unroll
                for (int j = 0; j < 10; ++j) {
                    float4 qv = *(float4*)&qs[(ug * 10 + j) * DIM + d];
                    acc[j] = fmaf(qv.x, kv.x, acc[j]);
                    acc[j] = fmaf(qv.y, kv.y, acc[j]);
                    acc[j] = fmaf(qv.z, kv.z, acc[j]);
                    acc[j] = fmaf(qv.w, kv.w, acc[j]);
                }
            }
            #pragma unroll
            for (int j = 0; j < 10; ++j) ps[(ug * 10 + j) * 68 + k] = acc[j] * 0.125f;
        }
        __syncthreads();

        for (int i = tid; i < 64 * DIM / 8; i += 256) {
            int r = i >> 3, dv = (i & 7) * 8;
            const float* vp = Vg + ((size_t)(b * L_SEQ + k0 + r) * NH + h) * DIM + dv;
            *(float4*)&ks[r * 68 + dv]     = *(const float4*)vp;
            *(float4*)&ks[r * 68 + dv + 4] = *(const float4*)(vp + 4);
        }
        if (tid < UU) {
            float mc = -INFINITY;
            for (int k = 0; k < 64; ++k) mc = fmaxf(mc, ps[tid * 68 + k]);
            float mn = fmaxf(mm[tid], mc);
            float a = __expf(mm[tid] - mn);
            float s = 0.f;
            for (int k = 0; k < 64; ++k) {
                float e = __expf(ps[tid * 68 + k] - mn);
                ps[tid * 68 + k] = e;
                s += e;
            }
            ll[tid] = ll[tid] * a + s;
            mm[tid] = mn;
            al[tid] = a;
        }
        __syncthreads();

        {
            #pragma unroll
            for (int j = 0; j < 5; ++j) {
                float a = al[ugp * 5 + j];
                o0[j] *= a; o1[j] *= a;
            }
            for (int k = 0; k < 64; k += 4) {
                float vf0[4], vf1[4];
                #pragma unroll
                for (int kk = 0; kk < 4; ++kk) {
                    float2 vv = *(float2*)&ks[(k + kk) * 68 + d0];
                    vf0[kk] = vv.x;
                    vf1[kk] = vv.y;
                }
                #pragma unroll
                for (int j = 0; j < 5; ++j) {
                    float4 pv = *(float4*)&ps[(ugp * 5 + j) * 68 + k];
                    o0[j] = fmaf(pv.x, vf0[0], o0[j]); o1[j] = fmaf(pv.x, vf1[0], o1[j]);
                    o0[j] = fmaf(pv.y, vf0[1], o0[j]); o1[j] = fmaf(pv.y, vf1[1], o1[j]);
                    o0[j] = fmaf(pv.z, vf0[2], o0[j]); o1[j] = fmaf(pv.z, vf1[2], o1[j]);
                    o0[j] = fmaf(pv.w, vf0[3], o0[j]); o1[j] = fmaf(pv.w, vf1[3], o1[j]);
                }
            }
        }
    }

    if (!direct) {
        if (tid < UU) {
            pm[((size_t)bh * nsplit + sp) * UU + tid] = mm[tid];
            pl[((size_t)bh * nsplit + sp) * UU + tid] = ll[tid];
        }
        size_t basep = ((size_t)bh * nsplit + sp) * UU * DIM;
        #pragma unroll
        for (int j = 0; j < 5; ++j) {
            *(float2*)&pO[basep + (size_t)(ugp * 5 + j) * DIM + d0] = make_float2(o0[j], o1[j]);
        }
    } else {
        #pragma unroll
        for (int j = 0; j < 5; ++j) {
            int u = ugp * 5 + j;
            int row = mt[u];
            float inv = 1.0f / ll[u];
            size_t o = ((size_t)(b * L_SEQ + row) * NH + h) * DIM + d0;
            out[o]     = o0[j] * inv;
            out[o + 1] = o1[j] * inv;
        }
    }
}

// ======================= fused stage kernels =======================

// stage1: blocks [0,2048) m-score ; [2048,4096) csum8
__global__ __launch_bounds__(256) void stage1_kernel(const float* __restrict__ Qg,
                                                     const float* __restrict__ Kg,
                                                     const int* __restrict__ idx,
                                                     const float* __restrict__ Vg,
                                                     float* __restrict__ M,
                                                     float* __restrict__ cs8) {
    int bx = blockIdx.x, tid = threadIdx.x;
    if (bx < 2048) {
        m_body(Qg, Kg, idx, M, bx, tid);
    } else {
        int wid = (bx - 2048) * 4 + (tid >> 6);
        csum8_body(Vg, cs8, wid, tid & 63);
    }
}

// stage2: blocks [0,32) topk radix ; [32,64) prefix over cs8
__global__ __launch_bounds__(256) void stage2_kernel(const float* __restrict__ M,
                                                     int* __restrict__ Mtop,
                                                     float* __restrict__ cs8) {
    __shared__ unsigned hist[256];
    __shared__ unsigned suf[256];
    __shared__ int eq_list[64];
    __shared__ unsigned sh_bin, sh_need, sh_cnt, sh_eqc;
    __shared__ float buf[256 * 64];   // prefix branch (64 KB)
    int bx = blockIdx.x, tid = threadIdx.x;

    if (bx < 32) {
        int bh = bx;
        const float* Mrow = M + (size_t)bh * L_SEQ;
        int base = tid * 8;
        float4 a0 = *(const float4*)(Mrow + base);
        float4 a1 = *(const float4*)(Mrow + base + 4);
        float fv[8] = {a0.x, a0.y, a0.z, a0.w, a1.x, a1.y, a1.z, a1.w};
        unsigned key[8];
        #pragma unroll
        for (int j = 0; j < 8; ++j) {
            unsigned u = __float_as_uint(fv[j]);
            key[j] = (u & 0x80000000u) ? ~u : (u | 0x80000000u);
        }
        unsigned actmask = 0xffu;
        unsigned thresh = 0;
        int need = UU;
        #pragma unroll
        for (int shift = 24; shift >= 0; shift -= 8) {
            hist[tid] = 0;
            __syncthreads();
            #pragma unroll
            for (int j = 0; j < 8; ++j)
                if ((actmask >> j) & 1u)
                    atomicAdd(&hist[(key[j] >> shift) & 0xffu], 1u);
            __syncthreads();
            if (tid < 64) {
                int b0 = tid * 4;
                unsigned h0 = hist[b0], h1 = hist[b0 + 1], h2 = hist[b0 + 2], h3 = hist[b0 + 3];
                unsigned loc = h0 + h1 + h2 + h3;
                unsigned s = loc;
                #pragma unroll
                for (int off = 1; off < 64; off <<= 1) {
                    unsigned o = __shfl_down(s, off, 64);
                    if (tid + off < 64) s += o;
                }
                unsigned tail = s - loc;
                suf[b0 + 3] = tail;
                suf[b0 + 2] = tail + h3;
                suf[b0 + 1] = tail + h3 + h2;
                suf[b0 + 0] = tail + h3 + h2 + h1;
            }
            __syncthreads();
            {
                int sb = (int)suf[tid];
                if (sb < need && sb + (int)hist[tid] >= need) {
                    sh_bin = (unsigned)tid;
                    sh_need = (unsigned)(need - sb);
                }
            }
            __syncthreads();
            unsigned Bb = sh_bin;
            need = (int)sh_need;
            thresh = (thresh << 8) | Bb;
            #pragma unroll
            for (int j = 0; j < 8; ++j)
                if ((actmask >> j) & 1u)
                    if (((key[j] >> shift) & 0xffu) != Bb) actmask &= ~(1u << j);
            __syncthreads();
        }
        if (tid == 0) { sh_cnt = 0; sh_eqc = 0; }
        __syncthreads();
        int* op = Mtop + bh * UU;
        #pragma unroll
        for (int j = 0; j < 8; ++j) {
            if (key[j] > thresh) {
                unsigned p = atomicAdd(&sh_cnt, 1u);
                op[p] = base + j;
            } else if (key[j] == thresh) {
                unsigned p = atomicAdd(&sh_eqc, 1u);
                if (p < 64) eq_list[p] = base + j;
            }
        }
        __syncthreads();
        unsigned cnt = sh_cnt, eqc = sh_eqc;
        if ((int)eqc == need) {
            if (tid < (unsigned)need) op[cnt + tid] = eq_list[tid];
        } else if (tid == 0) {
            if (eqc <= 64u) {
                for (int t = 0; t < need; ++t) {
                    int mi = t;
                    for (int j = t + 1; j < (int)eqc; ++j)
                        if (eq_list[j] < eq_list[mi]) mi = j;
                    int tmp = eq_list[t]; eq_list[t] = eq_list[mi]; eq_list[mi] = tmp;
                    op[cnt + t] = eq_list[t];
                }
            } else {
                int taken = 0;
                for (int i = 0; i < L_SEQ && taken < need; ++i) {
                    unsigned u = __float_as_uint(Mrow[i]);
                    unsigned k = (u & 0x80000000u) ? ~u : (u | 0x80000000u);
                    if (k == thresh) op[cnt + taken++] = i;
                }
            }
        }
    } else {
        // prefix8 over cs8 for bh = bx-32
        int bh = bx - 32;
        float* g = cs8 + (size_t)bh * 16384;
        for (int it = 0; it < 16; ++it) {
            int i = it * 1024 + tid * 4;
            *(float4*)&buf[i] = *(const float4*)&g[i];
        }
        __syncthreads();
        if (tid < 64) {
            float run = 0.f;
            for (int c = 0; c < 256; ++c) {
                float t = buf[c * 64 + tid];
                buf[c * 64 + tid] = run;
                run += t;
            }
        }
        __syncthreads();
        for (int it = 0; it < 16; ++it) {
            int i = it * 1024 + tid * 4;
            *(float4*)&g[i] = *(const float4*)&buf[i];
        }
    }
}

// stage3: blocks [0,nattn) attention partials ; [nattn, nattn+2048) cumsum write
__global__ __launch_bounds__(256) void stage3_kernel(const float* __restrict__ Qg,
                                                     const float* __restrict__ Kg,
                                                     const float* __restrict__ Vg,
                                                     const int* __restrict__ Mtop,
                                                     const float* __restrict__ cs8,
                                                     float* __restrict__ pm,
                                                     float* __restrict__ pl,
                                                     float* __restrict__ pO,
                                                     float* __restrict__ out,
                                                     int nattn, int nsplit) {
    __shared__ float qs[UU * DIM];
    __shared__ float ks[64 * 68];
    __shared__ float ps[UU * 68];
    __shared__ float mm[UU], ll[UU], al[UU];
    int bx = blockIdx.x, tid = threadIdx.x;
    if (bx < nattn) {
        attn_body(Qg, Kg, Vg, Mtop, pm, pl, pO, out, nsplit, 0, bx, tid,
                  qs, ks, ps, mm, ll, al);
    } else {
        int wid = (bx - nattn) * 4 + (tid >> 6);
        write8_body(Vg, cs8, out, wid, tid & 63);
    }
}

// standalone attention (fallback tiers; also direct mode)
__global__ __launch_bounds__(256) void attn_kernel(const float* __restrict__ Qg,
                                                   const float* __restrict__ Kg,
                                                   const float* __restrict__ Vg,
                                                   const int* __restrict__ Mtop,
                                                   float* __restrict__ pm,
                                                   float* __restrict__ pl,
                                                   float* __restrict__ pO,
                                                   float* __restrict__ out,
                                                   int nsplit, int direct) {
    __shared__ float qs[UU * DIM];
    __shared__ float ks[64 * 68];
    __shared__ float ps[UU * 68];
    __shared__ float mm[UU], ll[UU], al[UU];
    attn_body(Qg, Kg, Vg, Mtop, pm, pl, pO, out, nsplit, direct,
              blockIdx.x, threadIdx.x, qs, ks, ps, mm, ll, al);
}

// stage4: combine partials + scatter attn rows
__global__ __launch_bounds__(256) void combine_kernel(const float* __restrict__ pm,
                                                      const float* __restrict__ pl,
                                                      const float* __restrict__ pO,
                                                      const int* __restrict__ Mtop,
                                                      float* __restrict__ out, int nsplit) {
    int wid = blockIdx.x * 4 + (threadIdx.x >> 6);
    int lane = threadIdx.x & 63;
    int u = wid % UU;
    int bh = wid / UU;
    int b = bh >> 3, h = bh & 7;
    float mg = -INFINITY;
    for (int c = 0; c < nsplit; ++c) mg = fmaxf(mg, pm[((size_t)bh * nsplit + c) * UU + u]);
    float acc = 0.f, lsum = 0.f;
    for (int c = 0; c < nsplit; ++c) {
        size_t pb = ((size_t)bh * nsplit + c) * UU + u;
        float w = __expf(pm[pb] - mg);
        lsum = fmaf(pl[pb], w, lsum);
        acc = fmaf(w, pO[pb * DIM + lane], acc);
    }
    int row = Mtop[bh * UU + u];
    out[((size_t)(b * L_SEQ + row) * NH + h) * DIM + lane] = acc / lsum;
}

// fused cumsum fallback (ultra-slim ws)
__global__ __launch_bounds__(256) void csum_fused_kernel(const float* __restrict__ Vg,
                                                         float* __restrict__ out) {
    __shared__ float css[32 * 64];
    int bh = blockIdx.x, tid = threadIdx.x;
    int b = bh >> 3, h = bh & 7;
    int cc = tid >> 3, d8 = (tid & 7) * 8;
    size_t off = ((size_t)(b * L_SEQ + cc * 64) * NH + h) * DIM + d8;
    const float* Vp = Vg + off;
    float s[8];
    #pragma unroll
    for (int j = 0; j < 8; ++j) s[j] = 0.f;
    for (int l = 0; l < 64; ++l) {
        float4 r0 = *(const float4*)(Vp + (size_t)l * NHD);
        float4 r1 = *(const float4*)(Vp + (size_t)l * NHD + 4);
        s[0] += r0.x; s[1] += r0.y; s[2] += r0.z; s[3] += r0.w;
        s[4] += r1.x; s[5] += r1.y; s[6] += r1.z; s[7] += r1.w;
    }
    #pragma unroll
    for (int j = 0; j < 8; ++j) css[cc * 64 + d8 + j] = s[j];
    __syncthreads();
    if (tid < 64) {
        float run = 0.f;
        for (int c = 0; c < 32; ++c) {
            float t = css[c * 64 + tid];
            css[c * 64 + tid] = run;
            run += t;
        }
    }
    __syncthreads();
    float r8[8];
    #pragma unroll
    for (int j = 0; j < 8; ++j) r8[j] = css[cc * 64 + d8 + j];
    float* Op = out + off;
    for (int l = 0; l < 64; ++l) {
        float4 r0 = *(const float4*)(Vp + (size_t)l * NHD);
        float4 r1 = *(const float4*)(Vp + (size_t)l * NHD + 4);
        r8[0] += r0.x; r8[1] += r0.y; r8[2] += r0.z; r8[3] += r0.w;
        r8[4] += r1.x; r8[5] += r1.y; r8[6] += r1.z; r8[7] += r1.w;
        *(float4*)(Op + (size_t)l * NHD)     = make_float4(r8[0], r8[1], r8[2], r8[3]);
        *(float4*)(Op + (size_t)l * NHD + 4) = make_float4(r8[4], r8[5], r8[6], r8[7]);
    }
}

extern "C" void kernel_launch(void* const* d_in, const int* in_sizes, int n_in,
                              void* d_out, int out_size, void* d_ws, size_t ws_size,
                              hipStream_t stream) {
    const float* Q = (const float*)d_in[0];
    const float* K = (const float*)d_in[1];
    const float* V = (const float*)d_in[2];
    const int* idx = (const int*)d_in[3];
    float* out = (float*)d_out;
    float* wsf = (float*)d_ws;

    // ws layout (floats): M[65536] | Mtop[1280 int] | pm[1280n] | pl[1280n]
    //                     | pO[81920n] | cs8[524288]  => (591104 + 84480n)*4 bytes
    int n = 0;
    const int cands[5] = {32, 16, 8, 4, 2};
    for (int i = 0; i < 5; ++i) {
        size_t need = (size_t)(591104 + 84480 * cands[i]) * 4;
        if (ws_size >= need) { n = cands[i]; break; }
    }

    if (n > 0) {
        float* M    = wsf;
        int*   Mtop = (int*)(wsf + 65536);
        float* pm   = wsf + 66816;
        float* pl   = pm + 1280 * (size_t)n;
        float* pO   = pl + 1280 * (size_t)n;
        float* cs8  = pO + 81920 * (size_t)n;
        stage1_kernel<<<4096, 256, 0, stream>>>(Q, K, idx, V, M, cs8);
        stage2_kernel<<<64, 256, 0, stream>>>(M, Mtop, cs8);
        stage3_kernel<<<32 * n + 2048, 256, 0, stream>>>(Q, K, V, Mtop, cs8,
                                                         pm, pl, pO, out, 32 * n, n);
        combine_kernel<<<320, 256, 0, stream>>>(pm, pl, pO, Mtop, out, n);
    } else if (ws_size >= (size_t)(66816 + 524288) * 4) {
        // no room for partials: cumsum via stage3(nattn=0), then direct attention
        float* M    = wsf;
        int*   Mtop = (int*)(wsf + 65536);
        float* cs8  = wsf + 66816;
        stage1_kernel<<<4096, 256, 0, stream>>>(Q, K, idx, V, M, cs8);
        stage2_kernel<<<64, 256, 0, stream>>>(M, Mtop, cs8);
        stage3_kernel<<<2048, 256, 0, stream>>>(Q, K, V, Mtop, cs8,
                                                nullptr, nullptr, nullptr, out, 0, 1);
        attn_kernel<<<32, 256, 0, stream>>>(Q, K, V, Mtop, nullptr, nullptr, nullptr,
                                            out, 1, 1);
    } else {
        // ultra-slim: M staged in d_out (overwritten later), Mtop in ws
        float* M    = (float*)d_out;
        int*   Mtop = (int*)d_ws;
        stage1_kernel<<<2048, 256, 0, stream>>>(Q, K, idx, nullptr, M, nullptr);
        stage2_kernel<<<32, 256, 0, stream>>>(M, Mtop, nullptr);
        csum_fused_kernel<<<32, 256, 0, stream>>>(V, out);
        attn_kernel<<<32, 256, 0, stream>>>(Q, K, V, Mtop, nullptr, nullptr, nullptr,
                                            out, 1, 1);
    }
}